// Round 1
// baseline (124.977 us; speedup 1.0000x reference)
//
#include <hip/hip_runtime.h>

// ---------------------------------------------------------------------------
// Algebraic collapse of the whole model (see derivation in commit message):
//   X[b, s, p]  = x[b, 0, ti*64+pr, tk*64+pc],  s = 8*ti+tk, p = 64*pr+pc
//   scores[b,h,i,j] ~ A'_h * G[b,i,j] + Bk'_h * sX[b,j]   (+ j-const terms
//                     that cancel in softmax);  G = token Gram of raw X
//   out[b,i,p] = sum_j W[b,i,j] * X[b,j,p] + const0,
//   W[b,i,j]   = sum_h g_h * softmax_j(scores)_h
// ---------------------------------------------------------------------------

#define CONST_OFF 0                       // 16 floats: A'[4], Bk'[4], g[4], const0@12
#define SXP_OFF   16                      // 512*64 partial token sums
#define WT_OFF    (16 + 512*64)           // W transposed: [b][j][i], 8*4096
#define G_OFF     (WT_OFF + 8*4096)       // reduced Gram: [b][i][j], 8*4096
#define PART_OFF  (G_OFF + 8*4096)        // partial Grams: [512 blocks][4096]

// ---------------------------------------------------------------------------
// K0: contract weights into the 13 scalars the rest of the pipeline needs.
// ---------------------------------------------------------------------------
__global__ __launch_bounds__(128) void k0_consts(
    const float* __restrict__ w1, const float* __restrict__ b1,
    const float* __restrict__ wqkv, const float* __restrict__ wproj,
    const float* __restrict__ bproj, const float* __restrict__ w2,
    const float* __restrict__ b2, float* __restrict__ ws)
{
    __shared__ float arow[96], crow[96], pvec[32];
    int t = threadIdx.x;
    if (t < 96) {
        float sa = 0.f, sc = 0.f;
        for (int c = 0; c < 32; ++c) {
            float w = wqkv[t * 32 + c];
            sa += w * w1[c];
            sc += w * b1[c];
        }
        arow[t] = sa; crow[t] = sc;
    } else {
        int c = t - 96;
        float s = 0.f;
        for (int oc = 0; oc < 32; ++oc) s += w2[oc] * wproj[oc * 32 + c];
        pvec[c] = s;
    }
    __syncthreads();
    const float scale = 1.0f / (4096.0f * 2.8284271247461903f); // 1/(P*sqrt(d))
    if (t < 4) {
        int h = t;
        float A = 0.f, Bk = 0.f, g = 0.f;
        for (int dd = 0; dd < 8; ++dd) {
            int o = h * 8 + dd;
            A  += arow[o] * arow[32 + o];   // aq . ak
            Bk += crow[o] * arow[32 + o];   // cq . ak
            g  += pvec[o] * arow[64 + o];   // pvec . av  (head slice)
        }
        ws[CONST_OFF + t]     = A * scale;
        ws[CONST_OFF + 4 + t] = Bk * scale;
        ws[CONST_OFF + 8 + t] = g;
    } else if (t == 4) {
        float c0 = b2[0];
        for (int c = 0; c < 32; ++c)  c0 += pvec[c] * crow[64 + c]; // pvec . cv
        for (int oc = 0; oc < 32; ++oc) c0 += w2[oc] * bproj[oc];
        ws[CONST_OFF + 12] = c0;
    }
}

// ---------------------------------------------------------------------------
// K1: per-(b, pr) partial Gram over the 64 intra-columns of one intra-row.
// 512 blocks x 256 threads. LDS tile xs[64 tokens][68] (pad 68 keeps float4
// column-of-rows reads at uniform 2-way bank aliasing = free).
// Thread (tix,tjx) owns G[{tix+16u}][{tjx+16v}] (strided rows avoid the
// stride-4-row bank collapse).
// ---------------------------------------------------------------------------
__global__ __launch_bounds__(256) void k1_gram(const float* __restrict__ x,
                                               float* __restrict__ ws)
{
    __shared__ float xs[64 * 68];
    int b = blockIdx.x >> 6, pr = blockIdx.x & 63;
    int t = threadIdx.x;
    const float* xb = x + (size_t)b * 262144;
    #pragma unroll
    for (int k = 0; k < 4; ++k) {
        int q = t + 256 * k;             // float4 index within 8x512 row group
        int tj = q >> 7, col4 = q & 127;
        float4 v = *(const float4*)(xb + (tj * 64 + pr) * 512 + col4 * 4);
        int token = tj * 8 + (col4 >> 4);
        *(float4*)(&xs[token * 68 + (col4 & 15) * 4]) = v;
    }
    __syncthreads();

    int tix = t & 15, tjx = t >> 4;
    float acc[4][4];
    #pragma unroll
    for (int u = 0; u < 4; ++u)
        #pragma unroll
        for (int v = 0; v < 4; ++v) acc[u][v] = 0.f;

    #pragma unroll 4
    for (int cq = 0; cq < 16; ++cq) {
        float4 a[4], bb[4];
        #pragma unroll
        for (int u = 0; u < 4; ++u)
            a[u] = *(const float4*)(&xs[(tix + 16 * u) * 68 + 4 * cq]);
        #pragma unroll
        for (int v = 0; v < 4; ++v)
            bb[v] = *(const float4*)(&xs[(tjx + 16 * v) * 68 + 4 * cq]);
        #pragma unroll
        for (int u = 0; u < 4; ++u)
            #pragma unroll
            for (int v = 0; v < 4; ++v)
                acc[u][v] += a[u].x * bb[v].x + a[u].y * bb[v].y +
                             a[u].z * bb[v].z + a[u].w * bb[v].w;
    }

    float* part = ws + PART_OFF + (size_t)blockIdx.x * 4096;
    #pragma unroll
    for (int u = 0; u < 4; ++u)
        #pragma unroll
        for (int v = 0; v < 4; ++v)
            part[(tix + 16 * u) * 64 + (tjx + 16 * v)] = acc[u][v];

    if (t < 64) {                         // partial token sums for this pr
        float s = 0.f;
        for (int c = 0; c < 64; ++c) s += xs[t * 68 + c];
        ws[SXP_OFF + blockIdx.x * 64 + t] = s;
    }
}

// ---------------------------------------------------------------------------
// K2a: reduce 64 row-partials -> G[b][i][j]. 128 blocks x 256 threads.
// ---------------------------------------------------------------------------
__global__ __launch_bounds__(256) void k2a_reduce(float* __restrict__ ws)
{
    int b = blockIdx.x >> 4, chunk = blockIdx.x & 15;
    int e = chunk * 256 + threadIdx.x;
    const float* part = ws + PART_OFF + (size_t)(b * 64) * 4096;
    float s = 0.f;
    #pragma unroll 8
    for (int r = 0; r < 64; ++r) s += part[(size_t)r * 4096 + e];
    ws[G_OFF + b * 4096 + e] = s;
}

// ---------------------------------------------------------------------------
// K2b: per batch: softmax over heads and build W^T[b][j][i].
// 8 blocks x 256 threads (thread = (head, row i)).
// ---------------------------------------------------------------------------
__global__ __launch_bounds__(256) void k2b_attn(float* __restrict__ ws)
{
    __shared__ float G_s[64 * 65];
    __shared__ float sx_s[64];
    __shared__ float Wacc[64 * 65];
    int b = blockIdx.x, t = threadIdx.x;

    #pragma unroll
    for (int k = 0; k < 16; ++k) {
        int e = k * 256 + t;
        int i = e >> 6, j = e & 63;
        G_s[i * 65 + j]  = ws[G_OFF + b * 4096 + e];
        Wacc[i * 65 + j] = 0.f;
    }
    if (t < 64) {
        float s = 0.f;
        for (int r = 0; r < 64; ++r) s += ws[SXP_OFF + (b * 64 + r) * 64 + t];
        sx_s[t] = s;
    }
    __syncthreads();

    {
        int h = t >> 6, i = t & 63;
        float A  = ws[CONST_OFF + h];
        float Bk = ws[CONST_OFF + 4 + h];
        float g  = ws[CONST_OFF + 8 + h];
        float m = -1e30f;
        for (int j = 0; j < 64; ++j) {
            float s = A * G_s[i * 65 + j] + Bk * sx_s[j];
            m = fmaxf(m, s);
        }
        float Z = 0.f;
        for (int j = 0; j < 64; ++j) {
            float s = A * G_s[i * 65 + j] + Bk * sx_s[j];
            Z += __expf(s - m);
        }
        float coef = g / Z;
        for (int j = 0; j < 64; ++j) {
            float s = A * G_s[i * 65 + j] + Bk * sx_s[j];
            atomicAdd(&Wacc[i * 65 + j], coef * __expf(s - m));
        }
    }
    __syncthreads();

    int i = t & 63, jblk = t >> 6;
    #pragma unroll
    for (int jj = 0; jj < 16; ++jj) {
        int j = jblk * 16 + jj;
        ws[WT_OFF + b * 4096 + j * 64 + i] = Wacc[i * 65 + j];  // transposed
    }
}

// ---------------------------------------------------------------------------
// K3: out[b, ti*64+pr, tk*64+c] = const0 + sum_j W[b, 8ti+tk, j] * X_j(pr,c)
// 512 blocks x 256 threads; same LDS tiling as K1 plus staged W^T.
// ---------------------------------------------------------------------------
__global__ __launch_bounds__(256) void k3_apply(const float* __restrict__ x,
                                                const float* __restrict__ ws,
                                                float* __restrict__ out)
{
    __shared__ float xs[64 * 68];
    __shared__ float Wt_s[64 * 68];
    int b = blockIdx.x >> 6, pr = blockIdx.x & 63;
    int t = threadIdx.x;
    const float* xb = x + (size_t)b * 262144;
    #pragma unroll
    for (int k = 0; k < 4; ++k) {
        int q = t + 256 * k;
        int tj = q >> 7, col4 = q & 127;
        float4 v = *(const float4*)(xb + (tj * 64 + pr) * 512 + col4 * 4);
        int token = tj * 8 + (col4 >> 4);
        *(float4*)(&xs[token * 68 + (col4 & 15) * 4]) = v;
        // stage W^T: ws[WT_OFF + b*4096 + j*64 + i] -> Wt_s[j][i]
        int j = q >> 4, i0 = (q & 15) * 4;
        float4 wv = *(const float4*)(ws + WT_OFF + b * 4096 + q * 4);
        *(float4*)(&Wt_s[j * 68 + i0]) = wv;
    }
    __syncthreads();

    int tcx = t & 15, tiy = t >> 4;
    float acc[4][4];                       // [u = i offset][v = c offset]
    #pragma unroll
    for (int u = 0; u < 4; ++u)
        #pragma unroll
        for (int v = 0; v < 4; ++v) acc[u][v] = 0.f;

    #pragma unroll 8
    for (int j = 0; j < 64; ++j) {
        float4 wv = *(const float4*)(&Wt_s[j * 68 + 4 * tiy]); // 4 rows i
        float4 xv = *(const float4*)(&xs[j * 68 + 4 * tcx]);   // 4 cols c
        acc[0][0] += wv.x * xv.x; acc[0][1] += wv.x * xv.y;
        acc[0][2] += wv.x * xv.z; acc[0][3] += wv.x * xv.w;
        acc[1][0] += wv.y * xv.x; acc[1][1] += wv.y * xv.y;
        acc[1][2] += wv.y * xv.z; acc[1][3] += wv.y * xv.w;
        acc[2][0] += wv.z * xv.x; acc[2][1] += wv.z * xv.y;
        acc[2][2] += wv.z * xv.z; acc[2][3] += wv.z * xv.w;
        acc[3][0] += wv.w * xv.x; acc[3][1] += wv.w * xv.y;
        acc[3][2] += wv.w * xv.z; acc[3][3] += wv.w * xv.w;
    }

    float c0 = ws[CONST_OFF + 12];
    float* ob = out + (size_t)b * 262144;
    #pragma unroll
    for (int u = 0; u < 4; ++u) {
        int i = 4 * tiy + u;
        int ti = i >> 3, tk = i & 7;
        float4 r;
        r.x = acc[u][0] + c0; r.y = acc[u][1] + c0;
        r.z = acc[u][2] + c0; r.w = acc[u][3] + c0;
        *(float4*)(ob + (ti * 64 + pr) * 512 + tk * 64 + 4 * tcx) = r;
    }
}

extern "C" void kernel_launch(void* const* d_in, const int* in_sizes, int n_in,
                              void* d_out, int out_size, void* d_ws, size_t ws_size,
                              hipStream_t stream) {
    const float* x     = (const float*)d_in[0];
    // d_in[1] = n, d_in[2] = m  (fixed 8 by setup_inputs)
    const float* w1    = (const float*)d_in[3];
    const float* b1    = (const float*)d_in[4];
    const float* wqkv  = (const float*)d_in[5];
    const float* wproj = (const float*)d_in[6];
    const float* bproj = (const float*)d_in[7];
    const float* w2    = (const float*)d_in[8];
    const float* b2    = (const float*)d_in[9];
    float* out = (float*)d_out;
    float* ws  = (float*)d_ws;

    k0_consts<<<1, 128, 0, stream>>>(w1, b1, wqkv, wproj, bproj, w2, b2, ws);
    k1_gram<<<512, 256, 0, stream>>>(x, ws);
    k2a_reduce<<<128, 256, 0, stream>>>(ws);
    k2b_attn<<<8, 256, 0, stream>>>(ws);
    k3_apply<<<512, 256, 0, stream>>>(x, ws, out);
}